// Round 2
// baseline (575.806 us; speedup 1.0000x reference)
//
#include <hip/hip_runtime.h>
#include <hip/hip_bf16.h>
#include <math.h>

// ---------------- problem constants ----------------
#define M 8192
#define N 16384
#define D 64
#define ZC 58.81206612509905f        // 32*log(2*pi), h=1
#define B0 24.0f                     // exp2-domain bias (headroom; u<=0)
#define LOG2E 1.4426950408889634f
#define HL2E 0.7213475204444817f     // 0.5*log2(e)
#define LN2 0.6931471805599453f

#define PCH 32
#define NCHK (N / PCH)               // 512 train cols per block

typedef short v8bf __attribute__((ext_vector_type(8)));   // 8 bf16 (4 VGPRs)
typedef float v16f __attribute__((ext_vector_type(16)));

// ws layout (bytes)
#define B_AU2  0                        // 8192 f32  (32 KB)
#define B_LW2  32768                    // 16384 f32 (64 KB)
#define B_PART 98304                    // 32*8192 f32 (1 MB), [chunk][m]
#define B_TB   1146880                  // 8192*64 bf16 (1 MB)
#define B_TR   2195456                  // 16384*64 bf16 (2 MB)

// Fused prep: blocks 0..255 convert testX -> bf16(log2e*x) + au2;
// blocks 256..767 convert trainX -> bf16 + lw2 = log2(w) - hl2e*r2 + B0.
__global__ __launch_bounds__(256) void gk_prep(const float* __restrict__ testX,
                                               const float* __restrict__ trainX,
                                               const float* __restrict__ sw,
                                               __hip_bfloat16* __restrict__ tb,
                                               __hip_bfloat16* __restrict__ rb,
                                               float* __restrict__ au2,
                                               float* __restrict__ lw2) {
    const int tid = threadIdx.x;
    const int e = tid & 7;
    if (blockIdx.x < M / 32) {
        const int row = blockIdx.x * 32 + (tid >> 3);
        const float4* p = reinterpret_cast<const float4*>(testX + (size_t)row * D + e * 8);
        float4 v0 = p[0], v1 = p[1];
        float t2 = v0.x * v0.x + v0.y * v0.y + v0.z * v0.z + v0.w * v0.w
                 + v1.x * v1.x + v1.y * v1.y + v1.z * v1.z + v1.w * v1.w;
        t2 += __shfl_xor(t2, 1, 64);
        t2 += __shfl_xor(t2, 2, 64);
        t2 += __shfl_xor(t2, 4, 64);
        if (e == 0) au2[row] = -HL2E * t2;
        union { __hip_bfloat16 h[8]; uint4 u; } cv;
        cv.h[0] = __float2bfloat16(v0.x * LOG2E);
        cv.h[1] = __float2bfloat16(v0.y * LOG2E);
        cv.h[2] = __float2bfloat16(v0.z * LOG2E);
        cv.h[3] = __float2bfloat16(v0.w * LOG2E);
        cv.h[4] = __float2bfloat16(v1.x * LOG2E);
        cv.h[5] = __float2bfloat16(v1.y * LOG2E);
        cv.h[6] = __float2bfloat16(v1.z * LOG2E);
        cv.h[7] = __float2bfloat16(v1.w * LOG2E);
        *reinterpret_cast<uint4*>(tb + (size_t)row * D + e * 8) = cv.u;
    } else {
        const int row = (blockIdx.x - M / 32) * 32 + (tid >> 3);
        const float4* p = reinterpret_cast<const float4*>(trainX + (size_t)row * D + e * 8);
        float4 v0 = p[0], v1 = p[1];
        float r2 = v0.x * v0.x + v0.y * v0.y + v0.z * v0.z + v0.w * v0.w
                 + v1.x * v1.x + v1.y * v1.y + v1.z * v1.z + v1.w * v1.w;
        r2 += __shfl_xor(r2, 1, 64);
        r2 += __shfl_xor(r2, 2, 64);
        r2 += __shfl_xor(r2, 4, 64);
        if (e == 0) lw2[row] = __builtin_amdgcn_logf(sw[row]) - HL2E * r2 + B0;
        union { __hip_bfloat16 h[8]; uint4 u; } cv;
        cv.h[0] = __float2bfloat16(v0.x);
        cv.h[1] = __float2bfloat16(v0.y);
        cv.h[2] = __float2bfloat16(v0.z);
        cv.h[3] = __float2bfloat16(v0.w);
        cv.h[4] = __float2bfloat16(v1.x);
        cv.h[5] = __float2bfloat16(v1.y);
        cv.h[6] = __float2bfloat16(v1.z);
        cv.h[7] = __float2bfloat16(v1.w);
        *reinterpret_cast<uint4*>(rb + (size_t)row * D + e * 8) = cv.u;
    }
}

// Direct global->LDS DMA, 16 B/lane (no VGPR round-trip => nothing to spill).
__device__ __forceinline__ void dma16(const void* g, void* l) {
    __builtin_amdgcn_global_load_lds(
        (const __attribute__((address_space(1))) unsigned int*)g,
        (__attribute__((address_space(3))) unsigned int*)l, 16, 0, 0);
}

// Stage one 64x64 bf16 B-tile (8 KB) with 2 waves: wave w issues 4 DMAs;
// call g covers rows g*8..g*8+7: lane L fetches row g*8+(L&7), k-chunk
// (L>>3), landing at base+g*1024+L*16 =>
// LDS(rr,kc) = (rr>>3)*1024 + kc*128 + (rr&7)*16.
__device__ __forceinline__ void dma_tile(const __hip_bfloat16* tr, int nt,
                                         char* Bsb, int w, int lane) {
#pragma unroll
    for (int i = 0; i < 4; ++i) {
        const int g = w * 4 + i;
        const __hip_bfloat16* gp =
            tr + (size_t)(nt + g * 8 + (lane & 7)) * D + (lane >> 3) * 8;
        dma16(gp, Bsb + g * 1024);
    }
}

// Compute one 128(rows) x 64(cols) tile from LDS with 2 waves: each wave
// owns 2 row-groups (64 rows) so every B-fragment ds_read feeds TWO MFMAs
// (halves LDS traffic vs 4-wave/1-rg layout). lwa/lwb are this lane's bias
// values for col-subtiles 0/1, loaded a full tile EARLY (alongside the DMA)
// so tile start goes ds_read -> MFMA with no dependent global load.
__device__ __forceinline__ void compute_tile(const char* Bs, float lwa, float lwb,
                                             const v8bf af[2][4], float srun[32],
                                             int c, int h) {
#pragma unroll
    for (int s = 0; s < 2; ++s) {
        const float lwv = s ? lwb : lwa;
        v8bf bf[4];
#pragma unroll
        for (int t = 0; t < 4; ++t)
            bf[t] = *reinterpret_cast<const v8bf*>(
                Bs + (s * 4 + (c >> 3)) * 1024 + (2 * t + h) * 128 + (c & 7) * 16);
#pragma unroll
        for (int rg = 0; rg < 2; ++rg) {
            v16f acc;
#pragma unroll
            for (int r = 0; r < 16; ++r) acc[r] = lwv;
#pragma unroll
            for (int t = 0; t < 4; ++t)
                acc = __builtin_amdgcn_mfma_f32_32x32x16_bf16(af[rg][t], bf[t], acc, 0, 0, 0);
#pragma unroll
            for (int r = 0; r < 16; ++r)
                srun[rg * 16 + r] += __builtin_amdgcn_exp2f(acc[r]);
        }
    }
}

// Main: 128 test rows x 512 train cols per block, 128 threads (2 waves),
// each wave owns 64 rows. Grid = 64*32 = 2048 blocks = exactly 8/CU,
// single round. vs the 4-wave layout: B-fragment ds_reads halve (1 read ->
// 2 MFMAs) and the CU hosts 8 independent barrier domains instead of 4, so
// one block's DMA-drain stall overlaps another's MFMA+exp. LDS 16.9 KB x 8
// = 135 KB; (128,4) -> 4 waves/SIMD, VGPR cap 128 (est ~115 used).
__global__ __launch_bounds__(128, 4) void gk_main(const __hip_bfloat16* __restrict__ ta,
                                                  const __hip_bfloat16* __restrict__ tr,
                                                  const float* __restrict__ lw2,
                                                  float* __restrict__ part) {
    __shared__ __align__(16) char smem[16896];   // dbuf 2x8K; red 128x33 f32 reuses
    const int tid = threadIdx.x;
    const int w = tid >> 6;          // 0..1
    const int lane = tid & 63;
    const int c = lane & 31;
    const int h = lane >> 5;

    // XCD swizzle: xcd = bid&7 owns chunks 4x..4x+3 (2048 train rows L2-local)
    const int bid = blockIdx.x;
    const int xcd = bid & 7;
    const int j = bid >> 3;                 // 0..255
    const int chunk = xcd * 4 + (j & 3);    // 0..31
    const int m0 = (j >> 2) * 128;          // 64 m-tiles
    const int n0 = chunk * NCHK;

    char* const Bs0 = smem;
    char* const Bs1 = smem + 8192;

    // kick off tile 0 DMA + tile 0 bias loads, then A fragments while they fly
    dma_tile(tr, n0, Bs0, w, lane);
    float lwa0 = lw2[n0 + c], lwb0 = lw2[n0 + 32 + c];

    const __hip_bfloat16* arow = ta + (size_t)(m0 + w * 64 + c) * D;
    v8bf af[2][4];
#pragma unroll
    for (int rg = 0; rg < 2; ++rg)
#pragma unroll
        for (int t = 0; t < 4; ++t)
            af[rg][t] = *reinterpret_cast<const v8bf*>(
                arow + (size_t)rg * 32 * D + (2 * t + h) * 8);

    float srun[32];
#pragma unroll
    for (int r = 0; r < 32; ++r) srun[r] = 0.f;

    __syncthreads();                                   // tile0 staged

    // 8 tiles, ping-pong Bs0/Bs1; fully unrolled so all offsets are static.
#pragma unroll
    for (int s8 = 0; s8 < 4; ++s8) {
        const int t0 = s8 * 2;
        // odd tile t0+1 -> Bs1
        dma_tile(tr, n0 + (t0 + 1) * 64, Bs1, w, lane);
        const float lwa1 = lw2[n0 + (t0 + 1) * 64 + c];
        const float lwb1 = lw2[n0 + (t0 + 1) * 64 + 32 + c];
        compute_tile(Bs0, lwa0, lwb0, af, srun, c, h);
        __syncthreads();                               // tile t0+1 staged
        if (t0 + 2 < 8) {
            // even tile t0+2 -> Bs0
            dma_tile(tr, n0 + (t0 + 2) * 64, Bs0, w, lane);
            lwa0 = lw2[n0 + (t0 + 2) * 64 + c];
            lwb0 = lw2[n0 + (t0 + 2) * 64 + 32 + c];
        }
        compute_tile(Bs1, lwa1, lwb1, af, srun, c, h);
        __syncthreads();                               // tile t0+2 staged / drain
    }

    // ---- cross-lane row sum (cols live across 32 lanes) ----
    // last loop barrier already separates compute from smem reuse
    float* red = reinterpret_cast<float*>(smem);   // 128 x 33 f32 (16896 B)
#pragma unroll
    for (int rg = 0; rg < 2; ++rg)
#pragma unroll
        for (int r = 0; r < 16; ++r) {
            int rowl = (r & 3) + 8 * (r >> 2) + 4 * h;
            red[(w * 64 + rg * 32 + rowl) * 33 + c] = srun[rg * 16 + r];
        }
    __syncthreads();
    {
        float G = 0.f;
#pragma unroll
        for (int c2 = 0; c2 < 32; ++c2) G += red[tid * 33 + c2];
        part[(size_t)chunk * M + m0 + tid] = G;   // [chunk][m] coalesced
    }
}

__global__ __launch_bounds__(256) void gk_merge(const float* __restrict__ part,
                                                const float* __restrict__ au2,
                                                const float* __restrict__ sw,
                                                float* __restrict__ out) {
    __shared__ float red[256];
    const int tid = threadIdx.x;
    // W = sum(sw), recomputed per block (64 KB, L2-resident, fully parallel)
    float s = 0.f;
    const float4* p4 = reinterpret_cast<const float4*>(sw);
    for (int i = tid; i < N / 4; i += 256) {
        float4 v = p4[i];
        s += v.x + v.y + v.z + v.w;
    }
    red[tid] = s;
    __syncthreads();
    for (int off = 128; off > 0; off >>= 1) {
        if (tid < off) red[tid] += red[tid + off];
        __syncthreads();
    }
    const float W = red[0];

    const int r = blockIdx.x * 256 + tid;
    float G = 0.f;
#pragma unroll
    for (int p = 0; p < PCH; ++p) G += part[(size_t)p * M + r];
    out[r] = LN2 * (au2[r] + __builtin_amdgcn_logf(fmaxf(G, 1e-30f)) - B0
                   - __builtin_amdgcn_logf(W)) - ZC;
}

extern "C" void kernel_launch(void* const* d_in, const int* in_sizes, int n_in,
                              void* d_out, int out_size, void* d_ws, size_t ws_size,
                              hipStream_t stream) {
    const float* testX  = (const float*)d_in[0];   // [8192, 64]
    const float* trainX = (const float*)d_in[1];   // [16384, 64]
    const float* sw     = (const float*)d_in[2];   // [16384]
    float* out = (float*)d_out;                    // [8192]
    char* wsb = (char*)d_ws;

    float* au2  = (float*)(wsb + B_AU2);
    float* lw2  = (float*)(wsb + B_LW2);
    float* part = (float*)(wsb + B_PART);
    __hip_bfloat16* tb = (__hip_bfloat16*)(wsb + B_TB);
    __hip_bfloat16* rb = (__hip_bfloat16*)(wsb + B_TR);

    gk_prep<<<M / 32 + N / 32, 256, 0, stream>>>(testX, trainX, sw, tb, rb, au2, lw2);
    gk_main<<<(M / 128) * PCH, 128, 0, stream>>>(tb, rb, lw2, part);
    gk_merge<<<M / 256, 256, 0, stream>>>(part, au2, sw, out);
}

// Round 3
// 476.900 us; speedup vs baseline: 1.2074x; 1.2074x over previous
//
#include <hip/hip_runtime.h>
#include <hip/hip_bf16.h>
#include <math.h>

// ---------------- problem constants ----------------
#define M 8192
#define N 16384
#define D 64
#define ZC 58.81206612509905f        // 32*log(2*pi), h=1
#define B0 24.0f                     // exp2-domain bias (headroom; u<=0)
#define LOG2E 1.4426950408889634f
#define HL2E 0.7213475204444817f     // 0.5*log2(e)
#define LN2 0.6931471805599453f

#define PCH 32
#define NCHK (N / PCH)               // 512 train cols per block

typedef short v8bf __attribute__((ext_vector_type(8)));   // 8 bf16 (4 VGPRs)
typedef float v16f __attribute__((ext_vector_type(16)));

// ws layout (bytes)
#define B_AU2  0                        // 8192 f32  (32 KB)
#define B_LW2  32768                    // 16384 f32 (64 KB)
#define B_PART 98304                    // 32*8192 f32 (1 MB), [chunk][m]
#define B_TB   1146880                  // 8192*64 bf16 (1 MB)
#define B_TR   2195456                  // 16384*64 bf16 (2 MB)

// Fused prep: blocks 0..255 convert testX -> bf16(log2e*x) + au2;
// blocks 256..767 convert trainX -> bf16 + lw2 = log2(w) - hl2e*r2 + B0.
__global__ __launch_bounds__(256) void gk_prep(const float* __restrict__ testX,
                                               const float* __restrict__ trainX,
                                               const float* __restrict__ sw,
                                               __hip_bfloat16* __restrict__ tb,
                                               __hip_bfloat16* __restrict__ rb,
                                               float* __restrict__ au2,
                                               float* __restrict__ lw2) {
    const int tid = threadIdx.x;
    const int e = tid & 7;
    if (blockIdx.x < M / 32) {
        const int row = blockIdx.x * 32 + (tid >> 3);
        const float4* p = reinterpret_cast<const float4*>(testX + (size_t)row * D + e * 8);
        float4 v0 = p[0], v1 = p[1];
        float t2 = v0.x * v0.x + v0.y * v0.y + v0.z * v0.z + v0.w * v0.w
                 + v1.x * v1.x + v1.y * v1.y + v1.z * v1.z + v1.w * v1.w;
        t2 += __shfl_xor(t2, 1, 64);
        t2 += __shfl_xor(t2, 2, 64);
        t2 += __shfl_xor(t2, 4, 64);
        if (e == 0) au2[row] = -HL2E * t2;
        union { __hip_bfloat16 h[8]; uint4 u; } cv;
        cv.h[0] = __float2bfloat16(v0.x * LOG2E);
        cv.h[1] = __float2bfloat16(v0.y * LOG2E);
        cv.h[2] = __float2bfloat16(v0.z * LOG2E);
        cv.h[3] = __float2bfloat16(v0.w * LOG2E);
        cv.h[4] = __float2bfloat16(v1.x * LOG2E);
        cv.h[5] = __float2bfloat16(v1.y * LOG2E);
        cv.h[6] = __float2bfloat16(v1.z * LOG2E);
        cv.h[7] = __float2bfloat16(v1.w * LOG2E);
        *reinterpret_cast<uint4*>(tb + (size_t)row * D + e * 8) = cv.u;
    } else {
        const int row = (blockIdx.x - M / 32) * 32 + (tid >> 3);
        const float4* p = reinterpret_cast<const float4*>(trainX + (size_t)row * D + e * 8);
        float4 v0 = p[0], v1 = p[1];
        float r2 = v0.x * v0.x + v0.y * v0.y + v0.z * v0.z + v0.w * v0.w
                 + v1.x * v1.x + v1.y * v1.y + v1.z * v1.z + v1.w * v1.w;
        r2 += __shfl_xor(r2, 1, 64);
        r2 += __shfl_xor(r2, 2, 64);
        r2 += __shfl_xor(r2, 4, 64);
        if (e == 0) lw2[row] = __builtin_amdgcn_logf(sw[row]) - HL2E * r2 + B0;
        union { __hip_bfloat16 h[8]; uint4 u; } cv;
        cv.h[0] = __float2bfloat16(v0.x);
        cv.h[1] = __float2bfloat16(v0.y);
        cv.h[2] = __float2bfloat16(v0.z);
        cv.h[3] = __float2bfloat16(v0.w);
        cv.h[4] = __float2bfloat16(v1.x);
        cv.h[5] = __float2bfloat16(v1.y);
        cv.h[6] = __float2bfloat16(v1.z);
        cv.h[7] = __float2bfloat16(v1.w);
        *reinterpret_cast<uint4*>(rb + (size_t)row * D + e * 8) = cv.u;
    }
}

// Direct global->LDS DMA, 16 B/lane (no VGPR round-trip => nothing to spill).
__device__ __forceinline__ void dma16(const void* g, void* l) {
    __builtin_amdgcn_global_load_lds(
        (const __attribute__((address_space(1))) unsigned int*)g,
        (__attribute__((address_space(3))) unsigned int*)l, 16, 0, 0);
}

// Stage one 64x64 bf16 B-tile (8 KB): wave w issues 2 DMAs; call g covers
// rows g*8..g*8+7: lane L fetches row g*8+(L&7), k-chunk (L>>3), landing at
// base+g*1024+L*16 => LDS(rr,kc) = (rr>>3)*1024 + kc*128 + (rr&7)*16.
__device__ __forceinline__ void dma_tile(const __hip_bfloat16* tr, int nt,
                                         char* Bsb, int w, int lane) {
#pragma unroll
    for (int i = 0; i < 2; ++i) {
        const int g = w * 2 + i;
        const __hip_bfloat16* gp =
            tr + (size_t)(nt + g * 8 + (lane & 7)) * D + (lane >> 3) * 8;
        dma16(gp, Bsb + g * 1024);
    }
}

// Compute one 256(rows) x 64(cols) tile from LDS. Each wave owns 2
// row-groups (64 rows): every B-fragment ds_read feeds TWO MFMAs (halves
// per-CU LDS traffic vs the 1-rg layout) and the two acc chains interleave
// (better MFMA pipelining). lwa/lwb are this lane's bias values for
// col-subtiles 0/1, loaded a full tile EARLY (alongside the DMA) so tile
// start goes ds_read -> MFMA with no dependent global load.
__device__ __forceinline__ void compute_tile(const char* Bs, float lwa, float lwb,
                                             const v8bf af[2][4], float srun[32],
                                             int c, int h) {
#pragma unroll
    for (int s = 0; s < 2; ++s) {
        const float lwv = s ? lwb : lwa;
        v16f acc0, acc1;
#pragma unroll
        for (int r = 0; r < 16; ++r) { acc0[r] = lwv; acc1[r] = lwv; }
#pragma unroll
        for (int t = 0; t < 4; ++t) {
            const v8bf bf = *reinterpret_cast<const v8bf*>(
                Bs + (s * 4 + (c >> 3)) * 1024 + (2 * t + h) * 128 + (c & 7) * 16);
            acc0 = __builtin_amdgcn_mfma_f32_32x32x16_bf16(af[0][t], bf, acc0, 0, 0, 0);
            acc1 = __builtin_amdgcn_mfma_f32_32x32x16_bf16(af[1][t], bf, acc1, 0, 0, 0);
        }
#pragma unroll
        for (int r = 0; r < 16; ++r) srun[r]      += __builtin_amdgcn_exp2f(acc0[r]);
#pragma unroll
        for (int r = 0; r < 16; ++r) srun[16 + r] += __builtin_amdgcn_exp2f(acc1[r]);
    }
}

// Main: 256 test rows x 512 train cols per block, 256 threads (4 waves),
// each wave owns 64 rows (2 row-groups). Grid = 32*32 = 1024 = exactly
// 4/CU, single round. vs round-1: B-fragment ds_reads per CU halve (1 read
// -> 2 MFMAs), per-tile compute doubles vs the same DMA+barrier cost, and
// barriers per output halve. (256,3) caps VGPR at 170 so the ~118-reg
// demand cannot be force-spilled (round-2 failure mode); expected actual
// use <=128 keeps 4 blocks/CU. LDS 33 KB (dbuf 16 KB; 256x33 f32 red
// reuses) x 4 = 135 KB/CU.
__global__ __launch_bounds__(256, 3) void gk_main(const __hip_bfloat16* __restrict__ ta,
                                                  const __hip_bfloat16* __restrict__ tr,
                                                  const float* __restrict__ lw2,
                                                  float* __restrict__ part) {
    __shared__ __align__(16) char smem[33792];   // dbuf 2x8K; red 256x33 f32 reuses
    const int tid = threadIdx.x;
    const int w = tid >> 6;          // 0..3
    const int lane = tid & 63;
    const int c = lane & 31;
    const int h = lane >> 5;

    // XCD swizzle: xcd = bid&7 owns chunks 4x..4x+3 (2048 train rows L2-local)
    const int bid = blockIdx.x;
    const int xcd = bid & 7;
    const int j = bid >> 3;                 // 0..127
    const int chunk = xcd * 4 + (j & 3);    // 0..31
    const int m0 = (j >> 2) * 256;          // 32 m-tiles
    const int n0 = chunk * NCHK;

    char* const Bs0 = smem;
    char* const Bs1 = smem + 8192;

    // kick off tile 0 DMA + tile 0 bias loads, then A fragments while they fly
    dma_tile(tr, n0, Bs0, w, lane);
    float lwa0 = lw2[n0 + c], lwb0 = lw2[n0 + 32 + c];

    const __hip_bfloat16* arow = ta + (size_t)(m0 + w * 64 + c) * D;
    v8bf af[2][4];
#pragma unroll
    for (int rg = 0; rg < 2; ++rg)
#pragma unroll
        for (int t = 0; t < 4; ++t)
            af[rg][t] = *reinterpret_cast<const v8bf*>(
                arow + (size_t)rg * 32 * D + (2 * t + h) * 8);

    float srun[32];
#pragma unroll
    for (int r = 0; r < 32; ++r) srun[r] = 0.f;

    __syncthreads();                                   // tile0 staged

    // 8 tiles, ping-pong Bs0/Bs1; fully unrolled so all offsets are static.
#pragma unroll
    for (int s8 = 0; s8 < 4; ++s8) {
        const int t0 = s8 * 2;
        // odd tile t0+1 -> Bs1
        dma_tile(tr, n0 + (t0 + 1) * 64, Bs1, w, lane);
        const float lwa1 = lw2[n0 + (t0 + 1) * 64 + c];
        const float lwb1 = lw2[n0 + (t0 + 1) * 64 + 32 + c];
        compute_tile(Bs0, lwa0, lwb0, af, srun, c, h);
        __syncthreads();                               // tile t0+1 staged
        if (t0 + 2 < 8) {
            // even tile t0+2 -> Bs0
            dma_tile(tr, n0 + (t0 + 2) * 64, Bs0, w, lane);
            lwa0 = lw2[n0 + (t0 + 2) * 64 + c];
            lwb0 = lw2[n0 + (t0 + 2) * 64 + 32 + c];
        }
        compute_tile(Bs1, lwa1, lwb1, af, srun, c, h);
        __syncthreads();                               // tile t0+2 staged / drain
    }

    // ---- cross-lane row sum (cols live across 32 lanes) ----
    // last loop barrier already separates compute from smem reuse
    float* red = reinterpret_cast<float*>(smem);   // 256 x 33 f32 (33792 B)
#pragma unroll
    for (int rg = 0; rg < 2; ++rg)
#pragma unroll
        for (int r = 0; r < 16; ++r) {
            int rowl = (r & 3) + 8 * (r >> 2) + 4 * h;
            red[(w * 64 + rg * 32 + rowl) * 33 + c] = srun[rg * 16 + r];
        }
    __syncthreads();
    {
        float G = 0.f;
#pragma unroll
        for (int c2 = 0; c2 < 32; ++c2) G += red[tid * 33 + c2];
        part[(size_t)chunk * M + m0 + tid] = G;   // [chunk][m] coalesced
    }
}

__global__ __launch_bounds__(256) void gk_merge(const float* __restrict__ part,
                                                const float* __restrict__ au2,
                                                const float* __restrict__ sw,
                                                float* __restrict__ out) {
    __shared__ float red[256];
    const int tid = threadIdx.x;
    // W = sum(sw), recomputed per block (64 KB, L2-resident, fully parallel)
    float s = 0.f;
    const float4* p4 = reinterpret_cast<const float4*>(sw);
    for (int i = tid; i < N / 4; i += 256) {
        float4 v = p4[i];
        s += v.x + v.y + v.z + v.w;
    }
    red[tid] = s;
    __syncthreads();
    for (int off = 128; off > 0; off >>= 1) {
        if (tid < off) red[tid] += red[tid + off];
        __syncthreads();
    }
    const float W = red[0];

    const int r = blockIdx.x * 256 + tid;
    float G = 0.f;
#pragma unroll
    for (int p = 0; p < PCH; ++p) G += part[(size_t)p * M + r];
    out[r] = LN2 * (au2[r] + __builtin_amdgcn_logf(fmaxf(G, 1e-30f)) - B0
                   - __builtin_amdgcn_logf(W)) - ZC;
}

extern "C" void kernel_launch(void* const* d_in, const int* in_sizes, int n_in,
                              void* d_out, int out_size, void* d_ws, size_t ws_size,
                              hipStream_t stream) {
    const float* testX  = (const float*)d_in[0];   // [8192, 64]
    const float* trainX = (const float*)d_in[1];   // [16384, 64]
    const float* sw     = (const float*)d_in[2];   // [16384]
    float* out = (float*)d_out;                    // [8192]
    char* wsb = (char*)d_ws;

    float* au2  = (float*)(wsb + B_AU2);
    float* lw2  = (float*)(wsb + B_LW2);
    float* part = (float*)(wsb + B_PART);
    __hip_bfloat16* tb = (__hip_bfloat16*)(wsb + B_TB);
    __hip_bfloat16* rb = (__hip_bfloat16*)(wsb + B_TR);

    gk_prep<<<M / 32 + N / 32, 256, 0, stream>>>(testX, trainX, sw, tb, rb, au2, lw2);
    gk_main<<<(M / 256) * PCH, 256, 0, stream>>>(tb, rb, lw2, part);
    gk_merge<<<M / 256, 256, 0, stream>>>(part, au2, sw, out);
}

// Round 4
// 94.137 us; speedup vs baseline: 6.1167x; 5.0660x over previous
//
#include <hip/hip_runtime.h>
#include <hip/hip_bf16.h>
#include <math.h>

// ---------------- problem constants ----------------
#define M 8192
#define N 16384
#define D 64
#define ZC 58.81206612509905f        // 32*log(2*pi), h=1
#define B0 24.0f                     // exp2-domain bias (headroom; u<=0)
#define LOG2E 1.4426950408889634f
#define HL2E 0.7213475204444817f     // 0.5*log2(e)
#define LN2 0.6931471805599453f

#define PCH 16
#define NCHK (N / PCH)               // 1024 train cols per block

typedef short v8bf __attribute__((ext_vector_type(8)));   // 8 bf16 (4 VGPRs)
typedef float v16f __attribute__((ext_vector_type(16)));

// ws layout (bytes)
#define B_AU2  0                        // 8192 f32  (32 KB)
#define B_LW2  32768                    // 16384 f32 (64 KB)
#define B_PART 98304                    // 16*8192 f32 (512 KB), [chunk][m]
#define B_TB   622592                   // 8192*64 bf16 (1 MB)
#define B_TR   1671168                  // 16384*64 bf16 (2 MB)

// Fused prep: blocks 0..255 convert testX -> bf16(log2e*x) + au2;
// blocks 256..767 convert trainX -> bf16 + lw2 = log2(w) - hl2e*r2 + B0.
__global__ __launch_bounds__(256) void gk_prep(const float* __restrict__ testX,
                                               const float* __restrict__ trainX,
                                               const float* __restrict__ sw,
                                               __hip_bfloat16* __restrict__ tb,
                                               __hip_bfloat16* __restrict__ rb,
                                               float* __restrict__ au2,
                                               float* __restrict__ lw2) {
    const int tid = threadIdx.x;
    const int e = tid & 7;
    if (blockIdx.x < M / 32) {
        const int row = blockIdx.x * 32 + (tid >> 3);
        const float4* p = reinterpret_cast<const float4*>(testX + (size_t)row * D + e * 8);
        float4 v0 = p[0], v1 = p[1];
        float t2 = v0.x * v0.x + v0.y * v0.y + v0.z * v0.z + v0.w * v0.w
                 + v1.x * v1.x + v1.y * v1.y + v1.z * v1.z + v1.w * v1.w;
        t2 += __shfl_xor(t2, 1, 64);
        t2 += __shfl_xor(t2, 2, 64);
        t2 += __shfl_xor(t2, 4, 64);
        if (e == 0) au2[row] = -HL2E * t2;
        union { __hip_bfloat16 h[8]; uint4 u; } cv;
        cv.h[0] = __float2bfloat16(v0.x * LOG2E);
        cv.h[1] = __float2bfloat16(v0.y * LOG2E);
        cv.h[2] = __float2bfloat16(v0.z * LOG2E);
        cv.h[3] = __float2bfloat16(v0.w * LOG2E);
        cv.h[4] = __float2bfloat16(v1.x * LOG2E);
        cv.h[5] = __float2bfloat16(v1.y * LOG2E);
        cv.h[6] = __float2bfloat16(v1.z * LOG2E);
        cv.h[7] = __float2bfloat16(v1.w * LOG2E);
        *reinterpret_cast<uint4*>(tb + (size_t)row * D + e * 8) = cv.u;
    } else {
        const int row = (blockIdx.x - M / 32) * 32 + (tid >> 3);
        const float4* p = reinterpret_cast<const float4*>(trainX + (size_t)row * D + e * 8);
        float4 v0 = p[0], v1 = p[1];
        float r2 = v0.x * v0.x + v0.y * v0.y + v0.z * v0.z + v0.w * v0.w
                 + v1.x * v1.x + v1.y * v1.y + v1.z * v1.z + v1.w * v1.w;
        r2 += __shfl_xor(r2, 1, 64);
        r2 += __shfl_xor(r2, 2, 64);
        r2 += __shfl_xor(r2, 4, 64);
        if (e == 0) lw2[row] = __builtin_amdgcn_logf(sw[row]) - HL2E * r2 + B0;
        union { __hip_bfloat16 h[8]; uint4 u; } cv;
        cv.h[0] = __float2bfloat16(v0.x);
        cv.h[1] = __float2bfloat16(v0.y);
        cv.h[2] = __float2bfloat16(v0.z);
        cv.h[3] = __float2bfloat16(v0.w);
        cv.h[4] = __float2bfloat16(v1.x);
        cv.h[5] = __float2bfloat16(v1.y);
        cv.h[6] = __float2bfloat16(v1.z);
        cv.h[7] = __float2bfloat16(v1.w);
        *reinterpret_cast<uint4*>(rb + (size_t)row * D + e * 8) = cv.u;
    }
}

// Direct global->LDS DMA, 16 B/lane (no VGPR round-trip => nothing to spill).
__device__ __forceinline__ void dma16(const void* g, void* l) {
    __builtin_amdgcn_global_load_lds(
        (const __attribute__((address_space(1))) unsigned int*)g,
        (__attribute__((address_space(3))) unsigned int*)l, 16, 0, 0);
}

// Stage one 64x64 bf16 B-tile (8 KB): wave w issues 2 DMAs; call g covers
// rows g*8..g*8+7: lane L fetches row g*8+(L&7), k-chunk (L>>3), landing at
// base+g*1024+L*16 => LDS(rr,kc) = (rr>>3)*1024 + kc*128 + (rr&7)*16.
__device__ __forceinline__ void dma_tile(const __hip_bfloat16* tr, int nt,
                                         char* Bsb, int w, int lane) {
#pragma unroll
    for (int i = 0; i < 2; ++i) {
        const int g = w * 2 + i;
        const __hip_bfloat16* gp =
            tr + (size_t)(nt + g * 8 + (lane & 7)) * D + (lane >> 3) * 8;
        dma16(gp, Bsb + g * 1024);
    }
}

// Compute one 128(rows) x 64(cols) tile from LDS (round-1 proven shape:
// 1 row-group/wave; 2-rg variants spill — rounds 2/3). lwa/lwb are this
// lane's bias values for col-subtiles 0/1, loaded a full tile EARLY
// (alongside the DMA) so tile start goes ds_read -> MFMA directly.
__device__ __forceinline__ void compute_tile(const char* Bs, float lwa, float lwb,
                                             const v8bf af[4], float srun[16],
                                             int c, int h) {
#pragma unroll
    for (int s = 0; s < 2; ++s) {
        const float lwv = s ? lwb : lwa;
        v16f acc;
#pragma unroll
        for (int r = 0; r < 16; ++r) acc[r] = lwv;
#pragma unroll
        for (int t = 0; t < 4; ++t) {
            const v8bf bf = *reinterpret_cast<const v8bf*>(
                Bs + (s * 4 + (c >> 3)) * 1024 + (2 * t + h) * 128 + (c & 7) * 16);
            acc = __builtin_amdgcn_mfma_f32_32x32x16_bf16(af[t], bf, acc, 0, 0, 0);
        }
#pragma unroll
        for (int r = 0; r < 16; ++r)
            srun[r] += __builtin_amdgcn_exp2f(acc[r]);
    }
}

// Main: 128 test rows x 1024 train cols per block, 256 threads (4 waves),
// round-1 proven tile shape. Grid = 64*16 = 1024 = exactly 4/CU, single
// round. NEW vs round-1: triple-buffered LDS + counted vmcnt (T3/T4):
// per tile, 4 vmem ops/wave (2 global_load_lds + 2 lw2 bias loads); we
// wait `vmcnt(4)` before the barrier so tile t's ops are retired while
// tile t+1's 4 stay in flight ACROSS the barrier — never draining the
// DMA queue to 0 in the main loop (the __syncthreads vmcnt(0) drain was
// the per-tile stall). vmcnt(0) only at the last tile. All buffer/bias
// indices are static after full unroll (no scratch).
__global__ __launch_bounds__(256, 4) void gk_main(const __hip_bfloat16* __restrict__ ta,
                                                  const __hip_bfloat16* __restrict__ tr,
                                                  const float* __restrict__ lw2,
                                                  float* __restrict__ part) {
    __shared__ __align__(16) char smem[24576];   // 3 x 8 KB tiles; red 128x33 f32 reuses
    const int tid = threadIdx.x;
    const int w = tid >> 6;
    const int lane = tid & 63;
    const int c = lane & 31;
    const int h = lane >> 5;

    // XCD swizzle: xcd = bid&7 owns chunks 2x..2x+1 (2048 train rows L2-local)
    const int bid = blockIdx.x;
    const int xcd = bid & 7;
    const int j = bid >> 3;                 // 0..127
    const int chunk = xcd * 2 + (j & 1);    // 0..15
    const int m0 = (j >> 1) * 128;          // 64 m-tiles
    const int n0 = chunk * NCHK;

    char* const Bs[3] = { smem, smem + 8192, smem + 16384 };

    float lwa[3], lwb[3];

    // prologue: tile 0 DMA + bias, then A fragments, then tile 1 DMA + bias.
    // Issue order keeps tile-0 ops oldest so vmcnt(4) at t=0 retires them
    // (plus the af loads, which the compiler also waits on before MFMA).
    dma_tile(tr, n0, Bs[0], w, lane);
    lwa[0] = lw2[n0 + c]; lwb[0] = lw2[n0 + 32 + c];

    const __hip_bfloat16* arow = ta + (size_t)(m0 + w * 32 + c) * D;
    v8bf af[4];
#pragma unroll
    for (int t = 0; t < 4; ++t)
        af[t] = *reinterpret_cast<const v8bf*>(arow + (2 * t + h) * 8);

    dma_tile(tr, n0 + 64, Bs[1], w, lane);
    lwa[1] = lw2[n0 + 64 + c]; lwb[1] = lw2[n0 + 96 + c];

    float srun[16];
#pragma unroll
    for (int r = 0; r < 16; ++r) srun[r] = 0.f;

    // main loop: 16 tiles, fully unrolled (static %3 indices).
#pragma unroll
    for (int t = 0; t < 16; ++t) {
        if (t < 15) {
            asm volatile("s_waitcnt vmcnt(4)" ::: "memory");   // tile t landed; t+1 in flight
        } else {
            asm volatile("s_waitcnt vmcnt(0)" ::: "memory");   // last tile: full drain
        }
        __builtin_amdgcn_s_barrier();                          // all waves' tile-t data visible
        if (t + 2 < 16) {
            dma_tile(tr, n0 + (t + 2) * 64, Bs[(t + 2) % 3], w, lane);
            lwa[(t + 2) % 3] = lw2[n0 + (t + 2) * 64 + c];
            lwb[(t + 2) % 3] = lw2[n0 + (t + 2) * 64 + 32 + c];
        }
        compute_tile(Bs[t % 3], lwa[t % 3], lwb[t % 3], af, srun, c, h);
    }

    // ---- cross-lane row sum (cols live across 32 lanes) ----
    __syncthreads();                               // compute done; reuse smem
    float* red = reinterpret_cast<float*>(smem);   // 128 x 33 f32 (16896 B)
#pragma unroll
    for (int r = 0; r < 16; ++r) {
        int rowl = (r & 3) + 8 * (r >> 2) + 4 * h;
        red[(w * 32 + rowl) * 33 + c] = srun[r];
    }
    __syncthreads();
    if (tid < 128) {
        float G = 0.f;
#pragma unroll
        for (int c2 = 0; c2 < 32; ++c2) G += red[tid * 33 + c2];
        part[(size_t)chunk * M + m0 + tid] = G;   // [chunk][m] coalesced
    }
}

__global__ __launch_bounds__(256) void gk_merge(const float* __restrict__ part,
                                                const float* __restrict__ au2,
                                                const float* __restrict__ sw,
                                                float* __restrict__ out) {
    __shared__ float red[256];
    const int tid = threadIdx.x;
    // W = sum(sw), recomputed per block (64 KB, L2-resident, fully parallel)
    float s = 0.f;
    const float4* p4 = reinterpret_cast<const float4*>(sw);
    for (int i = tid; i < N / 4; i += 256) {
        float4 v = p4[i];
        s += v.x + v.y + v.z + v.w;
    }
    red[tid] = s;
    __syncthreads();
    for (int off = 128; off > 0; off >>= 1) {
        if (tid < off) red[tid] += red[tid + off];
        __syncthreads();
    }
    const float W = red[0];

    const int r = blockIdx.x * 256 + tid;
    float G = 0.f;
#pragma unroll
    for (int p = 0; p < PCH; ++p) G += part[(size_t)p * M + r];
    out[r] = LN2 * (au2[r] + __builtin_amdgcn_logf(fmaxf(G, 1e-30f)) - B0
                   - __builtin_amdgcn_logf(W)) - ZC;
}

extern "C" void kernel_launch(void* const* d_in, const int* in_sizes, int n_in,
                              void* d_out, int out_size, void* d_ws, size_t ws_size,
                              hipStream_t stream) {
    const float* testX  = (const float*)d_in[0];   // [8192, 64]
    const float* trainX = (const float*)d_in[1];   // [16384, 64]
    const float* sw     = (const float*)d_in[2];   // [16384]
    float* out = (float*)d_out;                    // [8192]
    char* wsb = (char*)d_ws;

    float* au2  = (float*)(wsb + B_AU2);
    float* lw2  = (float*)(wsb + B_LW2);
    float* part = (float*)(wsb + B_PART);
    __hip_bfloat16* tb = (__hip_bfloat16*)(wsb + B_TB);
    __hip_bfloat16* rb = (__hip_bfloat16*)(wsb + B_TR);

    gk_prep<<<M / 32 + N / 32, 256, 0, stream>>>(testX, trainX, sw, tb, rb, au2, lw2);
    gk_main<<<(M / 128) * PCH, 256, 0, stream>>>(tb, rb, lw2, part);
    gk_merge<<<M / 256, 256, 0, stream>>>(part, au2, sw, out);
}

// Round 5
// 92.959 us; speedup vs baseline: 6.1942x; 1.0127x over previous
//
#include <hip/hip_runtime.h>
#include <hip/hip_bf16.h>
#include <math.h>

// ---------------- problem constants ----------------
#define M 8192
#define N 16384
#define D 64
#define ZC 58.81206612509905f        // 32*log(2*pi), h=1
#define B0 24.0f                     // exp2-domain bias (headroom; u<=0)
#define LOG2E 1.4426950408889634f
#define HL2E 0.7213475204444817f     // 0.5*log2(e)
#define LN2 0.6931471805599453f

// Schraudolph exp2: 2^u ~= bitcast(int(u*2^23 + (127 - 0.0435)*2^23)).
// Bias-corrected midpoint => max rel err ~±3% (log-output err <= 0.04,
// same order as existing bf16 dot noise; tolerance 0.5).
#define SCH_K 8388608.0f             // 2^23
#define SCH_C (1065353216.0f - 0.0435f * 8388608.0f)

#define PCH 16
#define NCHK (N / PCH)               // 1024 train cols per block

typedef short v8bf __attribute__((ext_vector_type(8)));   // 8 bf16 (4 VGPRs)
typedef float v16f __attribute__((ext_vector_type(16)));

// ws layout (bytes)
#define B_AU2  0                        // 8192 f32  (32 KB)
#define B_LW2  32768                    // 16384 f32 (64 KB)
#define B_PART 98304                    // 16*8192 f32 (512 KB), [chunk][m]
#define B_TB   622592                   // 8192*64 bf16 (1 MB)
#define B_TR   1671168                  // 16384*64 bf16 (2 MB)

// Fused prep: blocks 0..255 convert testX -> bf16(log2e*x) + au2;
// blocks 256..767 convert trainX -> bf16 + lw2 = log2(w) - hl2e*r2 + B0.
__global__ __launch_bounds__(256) void gk_prep(const float* __restrict__ testX,
                                               const float* __restrict__ trainX,
                                               const float* __restrict__ sw,
                                               __hip_bfloat16* __restrict__ tb,
                                               __hip_bfloat16* __restrict__ rb,
                                               float* __restrict__ au2,
                                               float* __restrict__ lw2) {
    const int tid = threadIdx.x;
    const int e = tid & 7;
    if (blockIdx.x < M / 32) {
        const int row = blockIdx.x * 32 + (tid >> 3);
        const float4* p = reinterpret_cast<const float4*>(testX + (size_t)row * D + e * 8);
        float4 v0 = p[0], v1 = p[1];
        float t2 = v0.x * v0.x + v0.y * v0.y + v0.z * v0.z + v0.w * v0.w
                 + v1.x * v1.x + v1.y * v1.y + v1.z * v1.z + v1.w * v1.w;
        t2 += __shfl_xor(t2, 1, 64);
        t2 += __shfl_xor(t2, 2, 64);
        t2 += __shfl_xor(t2, 4, 64);
        if (e == 0) au2[row] = -HL2E * t2;
        union { __hip_bfloat16 h[8]; uint4 u; } cv;
        cv.h[0] = __float2bfloat16(v0.x * LOG2E);
        cv.h[1] = __float2bfloat16(v0.y * LOG2E);
        cv.h[2] = __float2bfloat16(v0.z * LOG2E);
        cv.h[3] = __float2bfloat16(v0.w * LOG2E);
        cv.h[4] = __float2bfloat16(v1.x * LOG2E);
        cv.h[5] = __float2bfloat16(v1.y * LOG2E);
        cv.h[6] = __float2bfloat16(v1.z * LOG2E);
        cv.h[7] = __float2bfloat16(v1.w * LOG2E);
        *reinterpret_cast<uint4*>(tb + (size_t)row * D + e * 8) = cv.u;
    } else {
        const int row = (blockIdx.x - M / 32) * 32 + (tid >> 3);
        const float4* p = reinterpret_cast<const float4*>(trainX + (size_t)row * D + e * 8);
        float4 v0 = p[0], v1 = p[1];
        float r2 = v0.x * v0.x + v0.y * v0.y + v0.z * v0.z + v0.w * v0.w
                 + v1.x * v1.x + v1.y * v1.y + v1.z * v1.z + v1.w * v1.w;
        r2 += __shfl_xor(r2, 1, 64);
        r2 += __shfl_xor(r2, 2, 64);
        r2 += __shfl_xor(r2, 4, 64);
        if (e == 0) lw2[row] = __builtin_amdgcn_logf(sw[row]) - HL2E * r2 + B0;
        union { __hip_bfloat16 h[8]; uint4 u; } cv;
        cv.h[0] = __float2bfloat16(v0.x);
        cv.h[1] = __float2bfloat16(v0.y);
        cv.h[2] = __float2bfloat16(v0.z);
        cv.h[3] = __float2bfloat16(v0.w);
        cv.h[4] = __float2bfloat16(v1.x);
        cv.h[5] = __float2bfloat16(v1.y);
        cv.h[6] = __float2bfloat16(v1.z);
        cv.h[7] = __float2bfloat16(v1.w);
        *reinterpret_cast<uint4*>(rb + (size_t)row * D + e * 8) = cv.u;
    }
}

// Direct global->LDS DMA, 16 B/lane (no VGPR round-trip => nothing to spill).
__device__ __forceinline__ void dma16(const void* g, void* l) {
    __builtin_amdgcn_global_load_lds(
        (const __attribute__((address_space(1))) unsigned int*)g,
        (__attribute__((address_space(3))) unsigned int*)l, 16, 0, 0);
}

// Stage one 64x64 bf16 B-tile (8 KB): wave w issues 2 DMAs; call g covers
// rows g*8..g*8+7: lane L fetches row g*8+(L&7), k-chunk (L>>3), landing at
// base+g*1024+L*16 => LDS(rr,kc) = (rr>>3)*1024 + kc*128 + (rr&7)*16.
__device__ __forceinline__ void dma_tile(const __hip_bfloat16* tr, int nt,
                                         char* Bsb, int w, int lane) {
#pragma unroll
    for (int i = 0; i < 2; ++i) {
        const int g = w * 2 + i;
        const __hip_bfloat16* gp =
            tr + (size_t)(nt + g * 8 + (lane & 7)) * D + (lane >> 3) * 8;
        dma16(gp, Bsb + g * 1024);
    }
}

// Compute one 128(rows) x 64(cols) tile from LDS. NEW vs round-4:
// (a) acc chain starts from persistent zero16 as the first MFMA's C input
//     (kills 32 v_mov acc-inits per tile);
// (b) exp2 replaced by Schraudolph bit-trick fused with the lw bias:
//     cs = fma(lw, 2^23, SCH_C) (2 fma/tile), then per element
//     t = fma(acc, 2^23, cs); t = max(t,0); srun += bitcast(int(t)).
//     fma+max+cvt+add (8 issue-cy) replaces mov+v_exp+add (>=12 cy) and
//     frees the trans pipe entirely (134M exps -> 0).
__device__ __forceinline__ void compute_tile(const char* Bs, float lwa, float lwb,
                                             const v8bf af[4], const v16f& zacc,
                                             float srun[16], int c, int h) {
#pragma unroll
    for (int s = 0; s < 2; ++s) {
        const float cs = fmaf(s ? lwb : lwa, SCH_K, SCH_C);
        const v8bf bf0 = *reinterpret_cast<const v8bf*>(
            Bs + (s * 4 + (c >> 3)) * 1024 + (0 + h) * 128 + (c & 7) * 16);
        v16f acc = __builtin_amdgcn_mfma_f32_32x32x16_bf16(af[0], bf0, zacc, 0, 0, 0);
#pragma unroll
        for (int t = 1; t < 4; ++t) {
            const v8bf bf = *reinterpret_cast<const v8bf*>(
                Bs + (s * 4 + (c >> 3)) * 1024 + (2 * t + h) * 128 + (c & 7) * 16);
            acc = __builtin_amdgcn_mfma_f32_32x32x16_bf16(af[t], bf, acc, 0, 0, 0);
        }
#pragma unroll
        for (int r = 0; r < 16; ++r) {
            float tv = fmaf(acc[r], SCH_K, cs);
            tv = fmaxf(tv, 0.0f);
            srun[r] += __int_as_float((int)tv);
        }
    }
}

// Main: 128 test rows x 1024 train cols per block, 256 threads (4 waves),
// round-1 proven tile shape; round-4 triple-buffer + counted vmcnt kept.
// Grid = 64*16 = 1024 = exactly 4/CU, single round. Per tile, 4 vmem
// ops/wave (2 global_load_lds + 2 lw2 bias loads); vmcnt(4) before the
// barrier keeps tile t+1's ops in flight across it; vmcnt(0) only at the
// last tile. Register est ~95 (af16+srun16+zacc16+acc16+bf8+misc) under
// the (256,4) 128 cap.
__global__ __launch_bounds__(256, 4) void gk_main(const __hip_bfloat16* __restrict__ ta,
                                                  const __hip_bfloat16* __restrict__ tr,
                                                  const float* __restrict__ lw2,
                                                  float* __restrict__ part) {
    __shared__ __align__(16) char smem[24576];   // 3 x 8 KB tiles; red 128x33 f32 reuses
    const int tid = threadIdx.x;
    const int w = tid >> 6;
    const int lane = tid & 63;
    const int c = lane & 31;
    const int h = lane >> 5;

    // XCD swizzle: xcd = bid&7 owns chunks 2x..2x+1 (2048 train rows L2-local)
    const int bid = blockIdx.x;
    const int xcd = bid & 7;
    const int j = bid >> 3;                 // 0..127
    const int chunk = xcd * 2 + (j & 1);    // 0..15
    const int m0 = (j >> 1) * 128;          // 64 m-tiles
    const int n0 = chunk * NCHK;

    char* const Bs[3] = { smem, smem + 8192, smem + 16384 };

    float lwa[3], lwb[3];

    // prologue: tile 0 DMA + bias, then A fragments, then tile 1 DMA + bias.
    dma_tile(tr, n0, Bs[0], w, lane);
    lwa[0] = lw2[n0 + c]; lwb[0] = lw2[n0 + 32 + c];

    const __hip_bfloat16* arow = ta + (size_t)(m0 + w * 32 + c) * D;
    v8bf af[4];
#pragma unroll
    for (int t = 0; t < 4; ++t)
        af[t] = *reinterpret_cast<const v8bf*>(arow + (2 * t + h) * 8);

    dma_tile(tr, n0 + 64, Bs[1], w, lane);
    lwa[1] = lw2[n0 + 64 + c]; lwb[1] = lw2[n0 + 96 + c];

    v16f zacc;
#pragma unroll
    for (int r = 0; r < 16; ++r) zacc[r] = 0.f;
    float srun[16];
#pragma unroll
    for (int r = 0; r < 16; ++r) srun[r] = 0.f;

    // main loop: 16 tiles, fully unrolled (static %3 indices).
#pragma unroll
    for (int t = 0; t < 16; ++t) {
        if (t < 15) {
            asm volatile("s_waitcnt vmcnt(4)" ::: "memory");   // tile t landed; t+1 in flight
        } else {
            asm volatile("s_waitcnt vmcnt(0)" ::: "memory");   // last tile: full drain
        }
        __builtin_amdgcn_s_barrier();                          // all waves' tile-t data visible
        if (t + 2 < 16) {
            dma_tile(tr, n0 + (t + 2) * 64, Bs[(t + 2) % 3], w, lane);
            lwa[(t + 2) % 3] = lw2[n0 + (t + 2) * 64 + c];
            lwb[(t + 2) % 3] = lw2[n0 + (t + 2) * 64 + 32 + c];
        }
        compute_tile(Bs[t % 3], lwa[t % 3], lwb[t % 3], af, zacc, srun, c, h);
    }

    // ---- cross-lane row sum (cols live across 32 lanes) ----
    __syncthreads();                               // compute done; reuse smem
    float* red = reinterpret_cast<float*>(smem);   // 128 x 33 f32 (16896 B)
#pragma unroll
    for (int r = 0; r < 16; ++r) {
        int rowl = (r & 3) + 8 * (r >> 2) + 4 * h;
        red[(w * 32 + rowl) * 33 + c] = srun[r];
    }
    __syncthreads();
    if (tid < 128) {
        float G = 0.f;
#pragma unroll
        for (int c2 = 0; c2 < 32; ++c2) G += red[tid * 33 + c2];
        part[(size_t)chunk * M + m0 + tid] = G;   // [chunk][m] coalesced
    }
}

__global__ __launch_bounds__(256) void gk_merge(const float* __restrict__ part,
                                                const float* __restrict__ au2,
                                                const float* __restrict__ sw,
                                                float* __restrict__ out) {
    __shared__ float red[256];
    const int tid = threadIdx.x;
    // W = sum(sw), recomputed per block (64 KB, L2-resident, fully parallel)
    float s = 0.f;
    const float4* p4 = reinterpret_cast<const float4*>(sw);
    for (int i = tid; i < N / 4; i += 256) {
        float4 v = p4[i];
        s += v.x + v.y + v.z + v.w;
    }
    red[tid] = s;
    __syncthreads();
    for (int off = 128; off > 0; off >>= 1) {
        if (tid < off) red[tid] += red[tid + off];
        __syncthreads();
    }
    const float W = red[0];

    const int r = blockIdx.x * 256 + tid;
    float G = 0.f;
#pragma unroll
    for (int p = 0; p < PCH; ++p) G += part[(size_t)p * M + r];
    out[r] = LN2 * (au2[r] + __builtin_amdgcn_logf(fmaxf(G, 1e-30f)) - B0
                   - __builtin_amdgcn_logf(W)) - ZC;
}

extern "C" void kernel_launch(void* const* d_in, const int* in_sizes, int n_in,
                              void* d_out, int out_size, void* d_ws, size_t ws_size,
                              hipStream_t stream) {
    const float* testX  = (const float*)d_in[0];   // [8192, 64]
    const float* trainX = (const float*)d_in[1];   // [16384, 64]
    const float* sw     = (const float*)d_in[2];   // [16384]
    float* out = (float*)d_out;                    // [8192]
    char* wsb = (char*)d_ws;

    float* au2  = (float*)(wsb + B_AU2);
    float* lw2  = (float*)(wsb + B_LW2);
    float* part = (float*)(wsb + B_PART);
    __hip_bfloat16* tb = (__hip_bfloat16*)(wsb + B_TB);
    __hip_bfloat16* rb = (__hip_bfloat16*)(wsb + B_TR);

    gk_prep<<<M / 32 + N / 32, 256, 0, stream>>>(testX, trainX, sw, tb, rb, au2, lw2);
    gk_main<<<(M / 128) * PCH, 256, 0, stream>>>(tb, rb, lw2, part);
    gk_merge<<<M / 256, 256, 0, stream>>>(part, au2, sw, out);
}